// Round 1
// baseline (383.265 us; speedup 1.0000x reference)
//
#include <hip/hip_runtime.h>
#include <hip/hip_bf16.h>

// ---------------------------------------------------------------------------
// GIN multi-task forward on MI355X.
// R18: MLP latency-hiding + conversion hoist. R17 counters: fused_mlp is
// latency-bound (MfmaUtil 6.8%, VALUBusy 11.3%, occ 29%, HBM 12.8%) with
// only 12 waves/CU resident and ~96 conversion-VALU ops per 24 MFMAs.
// Fixes: (a) 512-thr / 8-wave MLP blocks, each wave owns 32x32 (24 resident
// waves/CU, half the per-wave issue); (b) gather emits split-bf16 A planes
// (Ah/Al) directly - same bytes as fp32, zero stage-1 conversion VALU;
// (c) layer-1 MLP emits split-bf16 Ch/Cl only (25.6MB vs 38.4MB writes);
// layer-2 gather self-term = h+l (2^-17 rel err, negligible). CSR build,
// XCD-aligned gather swizzle (R17), pool, heads unchanged.
// ---------------------------------------------------------------------------

#define IN_DIM 128
#define NFINE 128        // fine dst buckets (16 per XCD)
#define BIN_EPB 4096     // edges per bin block (16/thread)
#define SRCCH 16         // src chunks per dst row (sorted order)
#define NSLOT 6400       // >= 391 * SRCCH
#define SPT 13           // scan slots per thread (512*13 >= 6400)

typedef float  f32x4  __attribute__((ext_vector_type(4)));
typedef short  bf16x4 __attribute__((ext_vector_type(4)));
typedef short  bf16x8 __attribute__((ext_vector_type(8)));

__device__ __forceinline__ unsigned short bf16_rne(float v) {
    unsigned u = __float_as_uint(v);
    unsigned t = u + 0x7fffu + ((u >> 16) & 1u);
    return (unsigned short)(t >> 16);
}

// ---------------- fp32 -> bf16 convert (RNE), 8 elems/thread ---------------

__global__ __launch_bounds__(256) void f32_to_bf16_kernel(
    const float4* __restrict__ in, uint4* __restrict__ out, int n8)
{
    int i = blockIdx.x * 256 + threadIdx.x;
    if (i >= n8) return;
    float4 a = in[i * 2];
    float4 b = in[i * 2 + 1];
    float v[8] = {a.x, a.y, a.z, a.w, b.x, b.y, b.z, b.w};
    unsigned r[4];
#pragma unroll
    for (int j = 0; j < 4; ++j)
        r[j] = (unsigned)bf16_rne(v[j * 2]) | ((unsigned)bf16_rne(v[j * 2 + 1]) << 16);
    out[i] = make_uint4(r[0], r[1], r[2], r[3]);
}

// ---------------- weight convert: W[k][n] fp32 -> Wt_h/Wt_l[n][k] bf16 -----

__global__ __launch_bounds__(256) void conv_weights_kernel(
    const float* __restrict__ W0, const float* __restrict__ W1,
    const float* __restrict__ W2, const float* __restrict__ W3,
    unsigned short* __restrict__ Wh, unsigned short* __restrict__ Wl)
{
    int m   = blockIdx.x >> 6;
    int idx = (blockIdx.x & 63) * 256 + threadIdx.x;
    const float* W = (m == 0) ? W0 : (m == 1) ? W1 : (m == 2) ? W2 : W3;
    int k = idx >> 7, n = idx & 127;
    float v = W[idx];
    unsigned short hh = bf16_rne(v);
    float hf = __uint_as_float(((unsigned)hh) << 16);
    unsigned short ll = bf16_rne(v - hf);
    Wh[m * 16384 + n * 128 + k] = hh;
    Wl[m * 16384 + n * 128 + k] = ll;
}

// ---------------- CSR build: 128-way bin -> fused hist/scan/fill -----------

__global__ __launch_bounds__(256) void bin_kernel(
    const int* __restrict__ src, const int* __restrict__ dst,
    int2* __restrict__ buckets, int* __restrict__ bcur,
    int n_edges, int n_nodes, int cap)
{
    __shared__ int cnt[NFINE];
    __shared__ int base[NFINE];
    for (int i = threadIdx.x; i < NFINE; i += 256) cnt[i] = 0;
    __syncthreads();

    const int e0 = blockIdx.x * BIN_EPB + threadIdx.x * 16;
    int ne = n_edges - e0;
    if (ne < 0) ne = 0;
    if (ne > 16) ne = 16;

    int d[16], s[16], off[16];
    if (ne == 16) {
#pragma unroll
        for (int q = 0; q < 4; ++q) {
            int4 dv = *(const int4*)(dst + e0 + q * 4);
            int4 sv = *(const int4*)(src + e0 + q * 4);
            d[q * 4 + 0] = dv.x; d[q * 4 + 1] = dv.y;
            d[q * 4 + 2] = dv.z; d[q * 4 + 3] = dv.w;
            s[q * 4 + 0] = sv.x; s[q * 4 + 1] = sv.y;
            s[q * 4 + 2] = sv.z; s[q * 4 + 3] = sv.w;
        }
    } else {
#pragma unroll
        for (int j = 0; j < 16; ++j) {
            d[j] = (j < ne) ? dst[e0 + j] : 0;
            s[j] = (j < ne) ? src[e0 + j] : 0;
        }
    }
#pragma unroll
    for (int j = 0; j < 16; ++j)
        if (j < ne) {
            int b = (int)(((long long)d[j] * NFINE) / n_nodes);
            off[j] = atomicAdd(&cnt[b], 1);
        }
    __syncthreads();
    for (int i = threadIdx.x; i < NFINE; i += 256)
        base[i] = atomicAdd(&bcur[i], cnt[i]);
    __syncthreads();
#pragma unroll
    for (int j = 0; j < 16; ++j)
        if (j < ne) {
            int b = (int)(((long long)d[j] * NFINE) / n_nodes);
            buckets[(size_t)b * cap + base[b] + off[j]] = make_int2(d[j], s[j]);
        }
}

// One block per fine bucket. Per-(node, src-chunk16) LDS histogram, blocked
// exclusive scan (13 slots/thread), row_start write, LDS-cursor fill ->
// csr rows stored sorted by src chunk (gather L2 locality).
__global__ __launch_bounds__(512) void csr_fused_kernel(
    const int2* __restrict__ buckets, const int* __restrict__ bcnt,
    int* __restrict__ row_start, int* __restrict__ csr_src,
    int cap, int n_nodes, int n_edges)
{
    __shared__ int bc[NFINE];
    __shared__ int h[NSLOT];
    __shared__ int tsum[512];
    __shared__ int bbase_s;

    const int b = blockIdx.x;
    const int t = threadIdx.x;
    const int lo_n = (int)(((long long)b * n_nodes + NFINE - 1) / NFINE);
    const int hi_n = (int)(((long long)(b + 1) * n_nodes + NFINE - 1) / NFINE);
    const int sl = hi_n - lo_n;

    if (t < NFINE) bc[t] = bcnt[t];
    for (int i = t; i < NSLOT; i += 512) h[i] = 0;
    __syncthreads();
    if (t == 0) {
        int s = 0;
        for (int i = 0; i < b; ++i) s += bc[i];
        bbase_s = s;
    }
    const int nb = bc[b];
    const int2* bp = buckets + (size_t)b * cap;
    __syncthreads();

    // pass 1: per-(node, src-chunk) histogram
    for (int i = t; i < nb; i += 512) {
        int2 e = bp[i];
        int key = (e.x - lo_n) * SRCCH + (int)(((long long)e.y * SRCCH) / n_nodes);
        atomicAdd(&h[key], 1);
    }
    __syncthreads();

    // blocked exclusive scan over NSLOT entries (SPT per thread)
    int base = 0;
#pragma unroll
    for (int j = 0; j < SPT; ++j) {
        int slot = t * SPT + j;
        if (slot < NSLOT) {
            int v = h[slot];
            h[slot] = base;
            base += v;
        }
    }
    tsum[t] = base;
    __syncthreads();
    for (int off = 1; off < 512; off <<= 1) {
        int tmp = (t >= off) ? tsum[t - off] : 0;
        __syncthreads();
        tsum[t] += tmp;
        __syncthreads();
    }
    int texcl = tsum[t] - base + bbase_s;
#pragma unroll
    for (int j = 0; j < SPT; ++j) {
        int slot = t * SPT + j;
        if (slot < NSLOT) h[slot] += texcl;
    }
    __syncthreads();
    for (int i = t; i < sl; i += 512) row_start[lo_n + i] = h[i * SRCCH];
    if (b == NFINE - 1 && t == 0) row_start[n_nodes] = n_edges;
    __syncthreads();

    // pass 2: fill with LDS cursors (exclusive csr window, full-line writes)
    for (int i = t; i < nb; i += 512) {
        int2 e = bp[i];
        int key = (e.x - lo_n) * SRCCH + (int)(((long long)e.y * SRCCH) / n_nodes);
        csr_src[atomicAdd(&h[key], 1)] = e.y;
    }
}

// ---------------- gather aggregation ---------------------------------------
// bf16 neighbors + (fp32 | split-bf16) self, fp32 accumulate, emits SPLIT
// bf16 planes (Ah/Al) so the MLP consumes MFMA operands directly (R18).
// R17 block->node-group swizzle kept: group g runs on XCD (g/4)%8 so MLP
// block j (groups 4j..4j+3) finds its A rows in XCD (j%8)'s L2.

__device__ __forceinline__ void add_row8(float acc[8], uint4 r) {
    union { unsigned u; float f; } c;
    c.u = r.x << 16;         acc[0] += c.f;
    c.u = r.x & 0xffff0000u; acc[1] += c.f;
    c.u = r.y << 16;         acc[2] += c.f;
    c.u = r.y & 0xffff0000u; acc[3] += c.f;
    c.u = r.z << 16;         acc[4] += c.f;
    c.u = r.z & 0xffff0000u; acc[5] += c.f;
    c.u = r.w << 16;         acc[6] += c.f;
    c.u = r.w & 0xffff0000u; acc[7] += c.f;
}

template <bool SELF_SPLIT>
__global__ __launch_bounds__(256) void gather_agg_bf16_kernel(
    const float* __restrict__ xf,    // fp32 self rows (if !SELF_SPLIT)
    const uint4* __restrict__ sh,    // self high plane (if SELF_SPLIT)
    const uint4* __restrict__ slo,   // self low plane  (if SELF_SPLIT)
    const uint4* __restrict__ xb,    // bf16 neighbor rows, 16 uint4/row
    const int* __restrict__ row_start, const int* __restrict__ csr_src,
    uint4* __restrict__ outh, uint4* __restrict__ outl, int n_nodes)
{
    // swizzle block -> 16-node group so group g lands on XCD (g/4)%8
    int blk = blockIdx.x;
    int nfull = (gridDim.x >> 5) << 5;   // multiple of 32
    int group;
    if (blk < nfull) {
        int x = blk & 7;
        int q = blk >> 3;
        group = ((q >> 2) << 5) + (x << 2) + (q & 3);
    } else {
        group = blk;                     // tail unswizzled
    }

    int node = group * 16 + (threadIdx.x >> 4);
    int lane = threadIdx.x & 15;
    if (node >= n_nodes) return;
    int lo = row_start[node];
    int hi = row_start[node + 1];

    float acc[8];
    if constexpr (SELF_SPLIT) {
        uint4 h = sh[(size_t)node * 16 + lane];
        uint4 l = slo[(size_t)node * 16 + lane];
#pragma unroll
        for (int j = 0; j < 8; ++j) acc[j] = 0.f;
        add_row8(acc, h);
        add_row8(acc, l);
    } else {
        const f32x4* xfr = (const f32x4*)(xf + (size_t)node * IN_DIM + lane * 8);
        f32x4 a0 = xfr[0];
        f32x4 a1 = xfr[1];
        acc[0] = a0.x; acc[1] = a0.y; acc[2] = a0.z; acc[3] = a0.w;
        acc[4] = a1.x; acc[5] = a1.y; acc[6] = a1.z; acc[7] = a1.w;
    }

    int e = lo;
    for (; e + 3 < hi; e += 4) {
        int s0 = csr_src[e];
        int s1 = csr_src[e + 1];
        int s2 = csr_src[e + 2];
        int s3 = csr_src[e + 3];
        uint4 r0 = xb[(size_t)s0 * 16 + lane];
        uint4 r1 = xb[(size_t)s1 * 16 + lane];
        uint4 r2 = xb[(size_t)s2 * 16 + lane];
        uint4 r3 = xb[(size_t)s3 * 16 + lane];
        add_row8(acc, r0);
        add_row8(acc, r1);
        add_row8(acc, r2);
        add_row8(acc, r3);
    }
    for (; e < hi; ++e) {
        uint4 r = xb[(size_t)csr_src[e] * 16 + lane];
        add_row8(acc, r);
    }

    // emit split bf16 (h + l), same 4B/elem as fp32 but MFMA-ready
    unsigned ph[4], pl[4];
#pragma unroll
    for (int j = 0; j < 4; ++j) {
        unsigned short h0 = bf16_rne(acc[2 * j]);
        unsigned short l0 = bf16_rne(acc[2 * j] - __uint_as_float(((unsigned)h0) << 16));
        unsigned short h1 = bf16_rne(acc[2 * j + 1]);
        unsigned short l1 = bf16_rne(acc[2 * j + 1] - __uint_as_float(((unsigned)h1) << 16));
        ph[j] = (unsigned)h0 | ((unsigned)h1 << 16);
        pl[j] = (unsigned)l0 | ((unsigned)l1 << 16);
    }
    outh[(size_t)node * 16 + lane] = make_uint4(ph[0], ph[1], ph[2], ph[3]);
    outl[(size_t)node * 16 + lane] = make_uint4(pl[0], pl[1], pl[2], pl[3]);
}

// ---------------- fused MLP: relu(relu(A@Wa+ba)@Wb+bb) ---------------------
// R18: 512 thr (8 waves) per 64-row x 128-col block; each wave owns a
// 32-row x 32-col quadrant (2x2 16x16 tiles, 12 MFMAs per k0-step). A comes
// in pre-split (Ah/Al bf16 planes) -> zero conversion VALU in stage 1.
// 24 resident waves/CU (vs 12 in R17) for latency hiding.
#define HSTRIDE 132

template <bool EMIT_SPLIT>
__global__ __launch_bounds__(512) void fused_mlp_kernel(
    const unsigned short* __restrict__ Ah, const unsigned short* __restrict__ Al,
    const unsigned short* __restrict__ Wa_h, const unsigned short* __restrict__ Wa_l,
    const float* __restrict__ ba,
    const unsigned short* __restrict__ Wb_h, const unsigned short* __restrict__ Wb_l,
    const float* __restrict__ bb,
    float* __restrict__ C, unsigned short* __restrict__ Ch,
    unsigned short* __restrict__ Cl, int M)
{
    __shared__ __align__(16) unsigned short Hh[64][HSTRIDE];
    __shared__ __align__(16) unsigned short Hl[64][HSTRIDE];

    const int t    = threadIdx.x;
    const int wave = t >> 6;
    const int lane = t & 63;
    const int l15  = lane & 15;
    const int quad = lane >> 4;
    const int rh   = (wave & 1) * 32;        // row half within block
    const int cq   = (wave >> 1) * 32;       // col quarter
    const int brow = blockIdx.x * 64;

    f32x4 acc[2][2];
#pragma unroll
    for (int ti = 0; ti < 2; ++ti)
#pragma unroll
        for (int ct = 0; ct < 2; ++ct) acc[ti][ct] = {0.f, 0.f, 0.f, 0.f};

    // ---- stage 1: A (global, pre-split bf16) @ Wa ----
    {
        int ar0 = brow + rh + l15;
        int ar1 = brow + rh + 16 + l15;
        if (ar0 >= M) ar0 = M - 1;
        if (ar1 >= M) ar1 = M - 1;
        const unsigned short* a0h = Ah + (size_t)ar0 * IN_DIM + quad * 8;
        const unsigned short* a0l = Al + (size_t)ar0 * IN_DIM + quad * 8;
        const unsigned short* a1h = Ah + (size_t)ar1 * IN_DIM + quad * 8;
        const unsigned short* a1l = Al + (size_t)ar1 * IN_DIM + quad * 8;
#pragma unroll
        for (int k0 = 0; k0 < IN_DIM; k0 += 32) {
            bf16x8 ah0 = *(const bf16x8*)(a0h + k0);
            bf16x8 al0 = *(const bf16x8*)(a0l + k0);
            bf16x8 ah1 = *(const bf16x8*)(a1h + k0);
            bf16x8 al1 = *(const bf16x8*)(a1l + k0);
#pragma unroll
            for (int ct = 0; ct < 2; ++ct) {
                const size_t woff = (size_t)(cq + ct * 16 + l15) * IN_DIM + k0 + quad * 8;
                bf16x8 wh = *(const bf16x8*)(Wa_h + woff);
                bf16x8 wl = *(const bf16x8*)(Wa_l + woff);
                acc[0][ct] = __builtin_amdgcn_mfma_f32_16x16x32_bf16(ah0, wh, acc[0][ct], 0, 0, 0);
                acc[1][ct] = __builtin_amdgcn_mfma_f32_16x16x32_bf16(ah1, wh, acc[1][ct], 0, 0, 0);
                acc[0][ct] = __builtin_amdgcn_mfma_f32_16x16x32_bf16(al0, wh, acc[0][ct], 0, 0, 0);
                acc[1][ct] = __builtin_amdgcn_mfma_f32_16x16x32_bf16(al1, wh, acc[1][ct], 0, 0, 0);
                acc[0][ct] = __builtin_amdgcn_mfma_f32_16x16x32_bf16(ah0, wl, acc[0][ct], 0, 0, 0);
                acc[1][ct] = __builtin_amdgcn_mfma_f32_16x16x32_bf16(ah1, wl, acc[1][ct], 0, 0, 0);
            }
        }
    }

    // ---- epilogue 1: h = relu(acc + ba) -> LDS quadrant (split bf16) ----
#pragma unroll
    for (int ti = 0; ti < 2; ++ti) {
#pragma unroll
        for (int ct = 0; ct < 2; ++ct) {
            int col = cq + ct * 16 + l15;
            float b = ba[col];
#pragma unroll
            for (int r = 0; r < 4; ++r) {
                int rl = rh + ti * 16 + quad * 4 + r;
                float v = fmaxf(acc[ti][ct][r] + b, 0.f);
                unsigned short hh = bf16_rne(v);
                Hh[rl][col] = hh;
                Hl[rl][col] = bf16_rne(v - __uint_as_float(((unsigned)hh) << 16));
            }
            acc[ti][ct] = {0.f, 0.f, 0.f, 0.f};
        }
    }
    __syncthreads();

    // ---- stage 2: h (LDS, split bf16) @ Wb ----
#pragma unroll
    for (int k0 = 0; k0 < IN_DIM; k0 += 32) {
        const int hk = k0 + quad * 8;
        bf16x8 ah[2], al[2];
#pragma unroll
        for (int ti = 0; ti < 2; ++ti) {
            const int hr = rh + ti * 16 + l15;
            bf16x4 h0 = *(const bf16x4*)&Hh[hr][hk];
            bf16x4 h1 = *(const bf16x4*)&Hh[hr][hk + 4];
            bf16x4 l0 = *(const bf16x4*)&Hl[hr][hk];
            bf16x4 l1 = *(const bf16x4*)&Hl[hr][hk + 4];
            ah[ti] = __builtin_shufflevector(h0, h1, 0, 1, 2, 3, 4, 5, 6, 7);
            al[ti] = __builtin_shufflevector(l0, l1, 0, 1, 2, 3, 4, 5, 6, 7);
        }
#pragma unroll
        for (int ct = 0; ct < 2; ++ct) {
            const size_t woff = (size_t)(cq + ct * 16 + l15) * IN_DIM + k0 + quad * 8;
            bf16x8 wh = *(const bf16x8*)(Wb_h + woff);
            bf16x8 wl = *(const bf16x8*)(Wb_l + woff);
            acc[0][ct] = __builtin_amdgcn_mfma_f32_16x16x32_bf16(ah[0], wh, acc[0][ct], 0, 0, 0);
            acc[1][ct] = __builtin_amdgcn_mfma_f32_16x16x32_bf16(ah[1], wh, acc[1][ct], 0, 0, 0);
            acc[0][ct] = __builtin_amdgcn_mfma_f32_16x16x32_bf16(al[0], wh, acc[0][ct], 0, 0, 0);
            acc[1][ct] = __builtin_amdgcn_mfma_f32_16x16x32_bf16(al[1], wh, acc[1][ct], 0, 0, 0);
            acc[0][ct] = __builtin_amdgcn_mfma_f32_16x16x32_bf16(ah[0], wl, acc[0][ct], 0, 0, 0);
            acc[1][ct] = __builtin_amdgcn_mfma_f32_16x16x32_bf16(ah[1], wl, acc[1][ct], 0, 0, 0);
        }
    }

    // ---- epilogue 2: out = relu(acc + bb) ----
#pragma unroll
    for (int ti = 0; ti < 2; ++ti) {
        const int rbase = brow + rh + ti * 16 + quad * 4;
#pragma unroll
        for (int ct = 0; ct < 2; ++ct) {
            int col = cq + ct * 16 + l15;
            float b = bb[col];
#pragma unroll
            for (int r = 0; r < 4; ++r) {
                int row = rbase + r;
                if (row < M) {
                    float o = fmaxf(acc[ti][ct][r] + b, 0.f);
                    if (EMIT_SPLIT) {
                        unsigned short hh = bf16_rne(o);
                        Ch[(size_t)row * IN_DIM + col] = hh;
                        Cl[(size_t)row * IN_DIM + col] =
                            bf16_rne(o - __uint_as_float(((unsigned)hh) << 16));
                    } else {
                        C[(size_t)row * IN_DIM + col] = o;
                    }
                }
            }
        }
    }
}

// ---------------- pool + heads ---------------------------------------------

__device__ __forceinline__ int lower_bound_i(const int* __restrict__ a, int n, int v) {
    int lo = 0, hi = n;
    while (lo < hi) {
        int mid = (lo + hi) >> 1;
        if (a[mid] < v) lo = mid + 1; else hi = mid;
    }
    return lo;
}

__global__ __launch_bounds__(128) void pool_kernel(
    const float* __restrict__ h, const int* __restrict__ batch,
    float* __restrict__ pooled, int n_nodes, int n_graphs)
{
    int g = blockIdx.x;
    int lo = lower_bound_i(batch, n_nodes, g);
    int hi = lower_bound_i(batch, n_nodes, g + 1);
    int j = threadIdx.x;
    float acc = 0.f;
    for (int i = lo; i < hi; ++i)
        acc += h[(size_t)i * IN_DIM + j];
    float cnt = (float)(hi - lo);
    pooled[(size_t)g * IN_DIM + j] = acc / fmaxf(cnt, 1.0f);
}

__global__ __launch_bounds__(64) void head_kernel(
    const float* __restrict__ pooled,
    const float* __restrict__ Ws,  const float* __restrict__ bs,
    const float* __restrict__ WlS, const float* __restrict__ blS,
    const float* __restrict__ WlP, const float* __restrict__ blP,
    const float* __restrict__ WnR, const float* __restrict__ bnR,
    float* __restrict__ out, int n_graphs)
{
    int g = blockIdx.x;
    int j = threadIdx.x;
    const float* p = pooled + (size_t)g * IN_DIM;
    float acc = bs[j];
#pragma unroll 8
    for (int k = 0; k < IN_DIM; ++k)
        acc = fmaf(p[k], Ws[k * 64 + j], acc);
    float gj = fmaxf(acc, 0.f);
    float s1 = gj * WlS[j];
    float s2 = gj * WlP[j];
    float s3 = gj * WnR[j];
#pragma unroll
    for (int off = 32; off > 0; off >>= 1) {
        s1 += __shfl_down(s1, off);
        s2 += __shfl_down(s2, off);
        s3 += __shfl_down(s3, off);
    }
    if (j == 0) {
        out[g]                = s1 + blS[0];
        out[n_graphs + g]     = s2 + blP[0];
        out[2 * n_graphs + g] = s3 + bnR[0];
    }
}

// ---------------- launch ---------------------------------------------------

extern "C" void kernel_launch(void* const* d_in, const int* in_sizes, int n_in,
                              void* d_out, int out_size, void* d_ws, size_t ws_size,
                              hipStream_t stream)
{
    const float* x   = (const float*)d_in[0];
    const int*   ei  = (const int*)d_in[1];
    const int*   bat = (const int*)d_in[2];
    const float* W1a = (const float*)d_in[3];
    const float* b1a = (const float*)d_in[4];
    const float* W1b = (const float*)d_in[5];
    const float* b1b = (const float*)d_in[6];
    const float* W2a = (const float*)d_in[7];
    const float* b2a = (const float*)d_in[8];
    const float* W2b = (const float*)d_in[9];
    const float* b2b = (const float*)d_in[10];
    const float* Ws  = (const float*)d_in[11];
    const float* bs  = (const float*)d_in[12];
    const float* WlS = (const float*)d_in[13];
    const float* blS = (const float*)d_in[14];
    const float* WlP = (const float*)d_in[15];
    const float* blP = (const float*)d_in[16];
    const float* WnR = (const float*)d_in[17];
    const float* bnR = (const float*)d_in[18];

    const int n_nodes  = in_sizes[0] / IN_DIM;
    const int n_edges  = in_sizes[1] / 2;
    const int n_graphs = out_size / 3;
    const int* src = ei;
    const int* dst = ei + n_edges;

    const size_t node_elems   = (size_t)n_nodes * IN_DIM;
    const size_t pooled_elems = (size_t)n_graphs * IN_DIM;

    // P1: Ah||Al split planes (gather out / MLP in); buckets alias (CSR phase)
    // P2: xb (bf16 of x) then Ch||Cl (layer-1 MLP out / layer-2 gather in)
    // P3: buf2 fp32 (layer-2 MLP out -> pool)
    float* P1     = (float*)d_ws;
    float* P2     = P1 + node_elems;
    float* P3     = P2 + node_elems;
    float* pooled = P3 + node_elems;
    int* row_start = (int*)(pooled + pooled_elems);   // n_nodes + 1
    int* bcur      = row_start + (n_nodes + 1);       // NFINE bucket cursors
    int* csr_src   = bcur + NFINE;                    // n_edges
    unsigned short* wt_h = (unsigned short*)(csr_src + n_edges);  // 4 * 16384
    unsigned short* wt_l = wt_h + 4 * 16384;

    unsigned short* Ah = (unsigned short*)P1;
    unsigned short* Al = Ah + node_elems;
    unsigned short* xb = (unsigned short*)P2;
    unsigned short* Ch = xb;                          // overwrites xb (dead after gather1)
    unsigned short* Cl = Ch + node_elems;

    const int cap = n_edges / NFINE + 2048;           // ~18 sigma slack
    int2* buckets = (int2*)P1;                        // 128*cap*8B ~= 15MB

    const int gatherblocks = (int)(((size_t)n_nodes * 16 + 255) / 256);
    const int mlpblocks = (n_nodes + 63) / 64;
    const int binblocks = (n_edges + BIN_EPB - 1) / BIN_EPB;
    const int n8 = (int)(node_elems / 8);
    const int cvtblocks = (n8 + 255) / 256;

    // ---- weight conversion + CSR build ----
    conv_weights_kernel<<<256, 256, 0, stream>>>(W1a, W1b, W2a, W2b, wt_h, wt_l);
    hipMemsetAsync(bcur, 0, NFINE * sizeof(int), stream);
    bin_kernel<<<binblocks, 256, 0, stream>>>(src, dst, buckets, bcur,
                                              n_edges, n_nodes, cap);
    csr_fused_kernel<<<NFINE, 512, 0, stream>>>(buckets, bcur, row_start,
                                                csr_src, cap, n_nodes, n_edges);

    // ---- layer 1 ----
    f32_to_bf16_kernel<<<cvtblocks, 256, 0, stream>>>((const float4*)x, (uint4*)xb, n8);
    gather_agg_bf16_kernel<false><<<gatherblocks, 256, 0, stream>>>(
        x, nullptr, nullptr, (const uint4*)xb, row_start, csr_src,
        (uint4*)Ah, (uint4*)Al, n_nodes);
    fused_mlp_kernel<true><<<mlpblocks, 512, 0, stream>>>(
        Ah, Al, wt_h, wt_l, b1a, wt_h + 16384, wt_l + 16384, b1b,
        nullptr, Ch, Cl, n_nodes);

    // ---- layer 2 ----
    gather_agg_bf16_kernel<true><<<gatherblocks, 256, 0, stream>>>(
        nullptr, (const uint4*)Ch, (const uint4*)Cl, (const uint4*)Ch,
        row_start, csr_src, (uint4*)Ah, (uint4*)Al, n_nodes);
    fused_mlp_kernel<false><<<mlpblocks, 512, 0, stream>>>(
        Ah, Al, wt_h + 2 * 16384, wt_l + 2 * 16384, b2a,
        wt_h + 3 * 16384, wt_l + 3 * 16384, b2b,
        P3, nullptr, nullptr, n_nodes);

    // ---- pool + heads ----
    pool_kernel<<<n_graphs, 128, 0, stream>>>(P3, bat, pooled, n_nodes, n_graphs);
    head_kernel<<<n_graphs, 64, 0, stream>>>(pooled, Ws, bs, WlS, blS, WlP, blP,
                                             WnR, bnR, (float*)d_out, n_graphs);
}

// Round 2
// 344.037 us; speedup vs baseline: 1.1140x; 1.1140x over previous
//
#include <hip/hip_runtime.h>
#include <hip/hip_bf16.h>

// ---------------------------------------------------------------------------
// GIN multi-task forward on MI355X.
// R19: gather->MLP FUSION. R18 post-mortem: doubling resident waves and
// removing all stage-1 conversion VALU left the MLP at ~54us (was 51) ->
// the MLP is bound by the global A round-trip (gather writes 25.6MB,
// MLP reads 25.6MB incl 13MB HBM fetch), not by TLP or issue work.
// Fix: one 512-thr block = 64 nodes. Phase G gathers those nodes
// (16 lanes/node, 2 sweeps of 32 nodes) and stores split-bf16 A planes
// into the SAME 33.8KB LDS buffer the MLP later reuses for H. Stage-1
// reads A from LDS like stage-2 reads H; only weight loads stay global
// (L2-resident). Deletes 51MB of global traffic + one dispatch per layer.
// CSR build, pool, heads unchanged. XCD swizzle dropped (A never leaves CU).
// ---------------------------------------------------------------------------

#define IN_DIM 128
#define NFINE 128        // fine dst buckets (16 per XCD)
#define BIN_EPB 4096     // edges per bin block (16/thread)
#define SRCCH 16         // src chunks per dst row (sorted order)
#define NSLOT 6400       // >= 391 * SRCCH
#define SPT 13           // scan slots per thread (512*13 >= 6400)

typedef float  f32x4  __attribute__((ext_vector_type(4)));
typedef short  bf16x4 __attribute__((ext_vector_type(4)));
typedef short  bf16x8 __attribute__((ext_vector_type(8)));

__device__ __forceinline__ unsigned short bf16_rne(float v) {
    unsigned u = __float_as_uint(v);
    unsigned t = u + 0x7fffu + ((u >> 16) & 1u);
    return (unsigned short)(t >> 16);
}

// ---------------- fp32 -> bf16 convert (RNE), 8 elems/thread ---------------

__global__ __launch_bounds__(256) void f32_to_bf16_kernel(
    const float4* __restrict__ in, uint4* __restrict__ out, int n8)
{
    int i = blockIdx.x * 256 + threadIdx.x;
    if (i >= n8) return;
    float4 a = in[i * 2];
    float4 b = in[i * 2 + 1];
    float v[8] = {a.x, a.y, a.z, a.w, b.x, b.y, b.z, b.w};
    unsigned r[4];
#pragma unroll
    for (int j = 0; j < 4; ++j)
        r[j] = (unsigned)bf16_rne(v[j * 2]) | ((unsigned)bf16_rne(v[j * 2 + 1]) << 16);
    out[i] = make_uint4(r[0], r[1], r[2], r[3]);
}

// ---------------- weight convert: W[k][n] fp32 -> Wt_h/Wt_l[n][k] bf16 -----

__global__ __launch_bounds__(256) void conv_weights_kernel(
    const float* __restrict__ W0, const float* __restrict__ W1,
    const float* __restrict__ W2, const float* __restrict__ W3,
    unsigned short* __restrict__ Wh, unsigned short* __restrict__ Wl)
{
    int m   = blockIdx.x >> 6;
    int idx = (blockIdx.x & 63) * 256 + threadIdx.x;
    const float* W = (m == 0) ? W0 : (m == 1) ? W1 : (m == 2) ? W2 : W3;
    int k = idx >> 7, n = idx & 127;
    float v = W[idx];
    unsigned short hh = bf16_rne(v);
    float hf = __uint_as_float(((unsigned)hh) << 16);
    unsigned short ll = bf16_rne(v - hf);
    Wh[m * 16384 + n * 128 + k] = hh;
    Wl[m * 16384 + n * 128 + k] = ll;
}

// ---------------- CSR build: 128-way bin -> fused hist/scan/fill -----------

__global__ __launch_bounds__(256) void bin_kernel(
    const int* __restrict__ src, const int* __restrict__ dst,
    int2* __restrict__ buckets, int* __restrict__ bcur,
    int n_edges, int n_nodes, int cap)
{
    __shared__ int cnt[NFINE];
    __shared__ int base[NFINE];
    for (int i = threadIdx.x; i < NFINE; i += 256) cnt[i] = 0;
    __syncthreads();

    const int e0 = blockIdx.x * BIN_EPB + threadIdx.x * 16;
    int ne = n_edges - e0;
    if (ne < 0) ne = 0;
    if (ne > 16) ne = 16;

    int d[16], s[16], off[16];
    if (ne == 16) {
#pragma unroll
        for (int q = 0; q < 4; ++q) {
            int4 dv = *(const int4*)(dst + e0 + q * 4);
            int4 sv = *(const int4*)(src + e0 + q * 4);
            d[q * 4 + 0] = dv.x; d[q * 4 + 1] = dv.y;
            d[q * 4 + 2] = dv.z; d[q * 4 + 3] = dv.w;
            s[q * 4 + 0] = sv.x; s[q * 4 + 1] = sv.y;
            s[q * 4 + 2] = sv.z; s[q * 4 + 3] = sv.w;
        }
    } else {
#pragma unroll
        for (int j = 0; j < 16; ++j) {
            d[j] = (j < ne) ? dst[e0 + j] : 0;
            s[j] = (j < ne) ? src[e0 + j] : 0;
        }
    }
#pragma unroll
    for (int j = 0; j < 16; ++j)
        if (j < ne) {
            int b = (int)(((long long)d[j] * NFINE) / n_nodes);
            off[j] = atomicAdd(&cnt[b], 1);
        }
    __syncthreads();
    for (int i = threadIdx.x; i < NFINE; i += 256)
        base[i] = atomicAdd(&bcur[i], cnt[i]);
    __syncthreads();
#pragma unroll
    for (int j = 0; j < 16; ++j)
        if (j < ne) {
            int b = (int)(((long long)d[j] * NFINE) / n_nodes);
            buckets[(size_t)b * cap + base[b] + off[j]] = make_int2(d[j], s[j]);
        }
}

// One block per fine bucket. Per-(node, src-chunk16) LDS histogram, blocked
// exclusive scan (13 slots/thread), row_start write, LDS-cursor fill ->
// csr rows stored sorted by src chunk (gather L2 locality).
__global__ __launch_bounds__(512) void csr_fused_kernel(
    const int2* __restrict__ buckets, const int* __restrict__ bcnt,
    int* __restrict__ row_start, int* __restrict__ csr_src,
    int cap, int n_nodes, int n_edges)
{
    __shared__ int bc[NFINE];
    __shared__ int h[NSLOT];
    __shared__ int tsum[512];
    __shared__ int bbase_s;

    const int b = blockIdx.x;
    const int t = threadIdx.x;
    const int lo_n = (int)(((long long)b * n_nodes + NFINE - 1) / NFINE);
    const int hi_n = (int)(((long long)(b + 1) * n_nodes + NFINE - 1) / NFINE);
    const int sl = hi_n - lo_n;

    if (t < NFINE) bc[t] = bcnt[t];
    for (int i = t; i < NSLOT; i += 512) h[i] = 0;
    __syncthreads();
    if (t == 0) {
        int s = 0;
        for (int i = 0; i < b; ++i) s += bc[i];
        bbase_s = s;
    }
    const int nb = bc[b];
    const int2* bp = buckets + (size_t)b * cap;
    __syncthreads();

    // pass 1: per-(node, src-chunk) histogram
    for (int i = t; i < nb; i += 512) {
        int2 e = bp[i];
        int key = (e.x - lo_n) * SRCCH + (int)(((long long)e.y * SRCCH) / n_nodes);
        atomicAdd(&h[key], 1);
    }
    __syncthreads();

    // blocked exclusive scan over NSLOT entries (SPT per thread)
    int base = 0;
#pragma unroll
    for (int j = 0; j < SPT; ++j) {
        int slot = t * SPT + j;
        if (slot < NSLOT) {
            int v = h[slot];
            h[slot] = base;
            base += v;
        }
    }
    tsum[t] = base;
    __syncthreads();
    for (int off = 1; off < 512; off <<= 1) {
        int tmp = (t >= off) ? tsum[t - off] : 0;
        __syncthreads();
        tsum[t] += tmp;
        __syncthreads();
    }
    int texcl = tsum[t] - base + bbase_s;
#pragma unroll
    for (int j = 0; j < SPT; ++j) {
        int slot = t * SPT + j;
        if (slot < NSLOT) h[slot] += texcl;
    }
    __syncthreads();
    for (int i = t; i < sl; i += 512) row_start[lo_n + i] = h[i * SRCCH];
    if (b == NFINE - 1 && t == 0) row_start[n_nodes] = n_edges;
    __syncthreads();

    // pass 2: fill with LDS cursors (exclusive csr window, full-line writes)
    for (int i = t; i < nb; i += 512) {
        int2 e = bp[i];
        int key = (e.x - lo_n) * SRCCH + (int)(((long long)e.y * SRCCH) / n_nodes);
        csr_src[atomicAdd(&h[key], 1)] = e.y;
    }
}

// ---------------- fused layer: gather + relu(relu(A@Wa+ba)@Wb+bb) ----------
// Block = 512 thr (8 waves) = 64 nodes = 64-row x 128-col output tile.
// Phase G: gather the 64 nodes (16 lanes/node, 2 sweeps of 32), fp32 acc,
// emit split-bf16 A planes into LDS. Phase 1: A(LDS)@Wa, per-wave 32x32
// quadrant. Epilogue-1 overwrites the same LDS with split-bf16 H.
// Phase 2: H(LDS)@Wb. Epilogue-2: split-bf16 Ch/Cl (layer 1) or fp32 C
// (layer 2) to global. Only global loads in phases 1/2 are weights.
#define HSTRIDE 132

__device__ __forceinline__ void add_row8(float acc[8], uint4 r) {
    union { unsigned u; float f; } c;
    c.u = r.x << 16;         acc[0] += c.f;
    c.u = r.x & 0xffff0000u; acc[1] += c.f;
    c.u = r.y << 16;         acc[2] += c.f;
    c.u = r.y & 0xffff0000u; acc[3] += c.f;
    c.u = r.z << 16;         acc[4] += c.f;
    c.u = r.z & 0xffff0000u; acc[5] += c.f;
    c.u = r.w << 16;         acc[6] += c.f;
    c.u = r.w & 0xffff0000u; acc[7] += c.f;
}

template <int LAYER>
__global__ __launch_bounds__(512) void fused_gin_layer_kernel(
    const float* __restrict__ xf,        // layer-1 self rows (fp32)
    const uint4* __restrict__ selfh,     // layer-2 self high plane
    const uint4* __restrict__ selfl,     // layer-2 self low plane
    const uint4* __restrict__ nbr,       // neighbor bf16 rows, 16 uint4/row
    const int* __restrict__ row_start, const int* __restrict__ csr_src,
    const unsigned short* __restrict__ Wa_h, const unsigned short* __restrict__ Wa_l,
    const float* __restrict__ ba,
    const unsigned short* __restrict__ Wb_h, const unsigned short* __restrict__ Wb_l,
    const float* __restrict__ bb,
    float* __restrict__ C, unsigned short* __restrict__ Ch,
    unsigned short* __restrict__ Cl, int M)
{
    __shared__ __align__(16) unsigned short Hh[64][HSTRIDE];
    __shared__ __align__(16) unsigned short Hl[64][HSTRIDE];

    const int t    = threadIdx.x;
    const int brow = blockIdx.x * 64;

    // ---- phase G: gather 64 nodes -> split-bf16 A planes in LDS ----
    {
        const int lane = t & 15;         // k-slice: elems [lane*8, lane*8+8)
        const int gr   = t >> 4;         // 0..31
#pragma unroll
        for (int it = 0; it < 2; ++it) {
            const int rl   = it * 32 + gr;
            const int node = brow + rl;
            float acc[8] = {0.f, 0.f, 0.f, 0.f, 0.f, 0.f, 0.f, 0.f};
            if (node < M) {
                if constexpr (LAYER == 1) {
                    const f32x4* xfr = (const f32x4*)(xf + (size_t)node * IN_DIM + lane * 8);
                    f32x4 a0 = xfr[0];
                    f32x4 a1 = xfr[1];
                    acc[0] = a0.x; acc[1] = a0.y; acc[2] = a0.z; acc[3] = a0.w;
                    acc[4] = a1.x; acc[5] = a1.y; acc[6] = a1.z; acc[7] = a1.w;
                } else {
                    add_row8(acc, selfh[(size_t)node * 16 + lane]);
                    add_row8(acc, selfl[(size_t)node * 16 + lane]);
                }
                const int lo = row_start[node];
                const int hi = row_start[node + 1];
                int e = lo;
                for (; e + 3 < hi; e += 4) {
                    int s0 = csr_src[e];
                    int s1 = csr_src[e + 1];
                    int s2 = csr_src[e + 2];
                    int s3 = csr_src[e + 3];
                    uint4 r0 = nbr[(size_t)s0 * 16 + lane];
                    uint4 r1 = nbr[(size_t)s1 * 16 + lane];
                    uint4 r2 = nbr[(size_t)s2 * 16 + lane];
                    uint4 r3 = nbr[(size_t)s3 * 16 + lane];
                    add_row8(acc, r0);
                    add_row8(acc, r1);
                    add_row8(acc, r2);
                    add_row8(acc, r3);
                }
                for (; e < hi; ++e)
                    add_row8(acc, nbr[(size_t)csr_src[e] * 16 + lane]);
            }
            unsigned short hh[8], ll[8];
#pragma unroll
            for (int j = 0; j < 8; ++j) {
                unsigned short h = bf16_rne(acc[j]);
                hh[j] = h;
                ll[j] = bf16_rne(acc[j] - __uint_as_float(((unsigned)h) << 16));
            }
            *(bf16x4*)&Hh[rl][lane * 8]     = *(const bf16x4*)&hh[0];
            *(bf16x4*)&Hh[rl][lane * 8 + 4] = *(const bf16x4*)&hh[4];
            *(bf16x4*)&Hl[rl][lane * 8]     = *(const bf16x4*)&ll[0];
            *(bf16x4*)&Hl[rl][lane * 8 + 4] = *(const bf16x4*)&ll[4];
        }
    }
    __syncthreads();

    // ---- MLP thread decomposition (R18): wave owns 32x32 quadrant ----
    const int wave = t >> 6;
    const int lane = t & 63;
    const int l15  = lane & 15;
    const int quad = lane >> 4;
    const int rh   = (wave & 1) * 32;        // row half within block
    const int cq   = (wave >> 1) * 32;       // col quarter

    f32x4 acc[2][2];
#pragma unroll
    for (int ti = 0; ti < 2; ++ti)
#pragma unroll
        for (int ct = 0; ct < 2; ++ct) acc[ti][ct] = {0.f, 0.f, 0.f, 0.f};

    // ---- phase 1: A (LDS, split bf16) @ Wa ----
#pragma unroll
    for (int k0 = 0; k0 < IN_DIM; k0 += 32) {
        const int hk = k0 + quad * 8;
        bf16x8 ah[2], al[2];
#pragma unroll
        for (int ti = 0; ti < 2; ++ti) {
            const int hr = rh + ti * 16 + l15;
            bf16x4 h0 = *(const bf16x4*)&Hh[hr][hk];
            bf16x4 h1 = *(const bf16x4*)&Hh[hr][hk + 4];
            bf16x4 l0 = *(const bf16x4*)&Hl[hr][hk];
            bf16x4 l1 = *(const bf16x4*)&Hl[hr][hk + 4];
            ah[ti] = __builtin_shufflevector(h0, h1, 0, 1, 2, 3, 4, 5, 6, 7);
            al[ti] = __builtin_shufflevector(l0, l1, 0, 1, 2, 3, 4, 5, 6, 7);
        }
#pragma unroll
        for (int ct = 0; ct < 2; ++ct) {
            const size_t woff = (size_t)(cq + ct * 16 + l15) * IN_DIM + k0 + quad * 8;
            bf16x8 wh = *(const bf16x8*)(Wa_h + woff);
            bf16x8 wl = *(const bf16x8*)(Wa_l + woff);
            acc[0][ct] = __builtin_amdgcn_mfma_f32_16x16x32_bf16(ah[0], wh, acc[0][ct], 0, 0, 0);
            acc[1][ct] = __builtin_amdgcn_mfma_f32_16x16x32_bf16(ah[1], wh, acc[1][ct], 0, 0, 0);
            acc[0][ct] = __builtin_amdgcn_mfma_f32_16x16x32_bf16(al[0], wh, acc[0][ct], 0, 0, 0);
            acc[1][ct] = __builtin_amdgcn_mfma_f32_16x16x32_bf16(al[1], wh, acc[1][ct], 0, 0, 0);
            acc[0][ct] = __builtin_amdgcn_mfma_f32_16x16x32_bf16(ah[0], wl, acc[0][ct], 0, 0, 0);
            acc[1][ct] = __builtin_amdgcn_mfma_f32_16x16x32_bf16(ah[1], wl, acc[1][ct], 0, 0, 0);
        }
    }
    __syncthreads();   // all stage-1 LDS reads done before H overwrite

    // ---- epilogue 1: h = relu(acc + ba) -> LDS (overwrite A planes) ----
#pragma unroll
    for (int ti = 0; ti < 2; ++ti) {
#pragma unroll
        for (int ct = 0; ct < 2; ++ct) {
            int col = cq + ct * 16 + l15;
            float b = ba[col];
#pragma unroll
            for (int r = 0; r < 4; ++r) {
                int rl = rh + ti * 16 + quad * 4 + r;
                float v = fmaxf(acc[ti][ct][r] + b, 0.f);
                unsigned short hh = bf16_rne(v);
                Hh[rl][col] = hh;
                Hl[rl][col] = bf16_rne(v - __uint_as_float(((unsigned)hh) << 16));
            }
            acc[ti][ct] = {0.f, 0.f, 0.f, 0.f};
        }
    }
    __syncthreads();

    // ---- phase 2: h (LDS, split bf16) @ Wb ----
#pragma unroll
    for (int k0 = 0; k0 < IN_DIM; k0 += 32) {
        const int hk = k0 + quad * 8;
        bf16x8 ah[2], al[2];
#pragma unroll
        for (int ti = 0; ti < 2; ++ti) {
            const int hr = rh + ti * 16 + l15;
            bf16x4 h0 = *(const bf16x4*)&Hh[hr][hk];
            bf16x4 h1 = *(const bf16x4*)&Hh[hr][hk + 4];
            bf16x4 l0 = *(const bf16x4*)&Hl[hr][hk];
            bf16x4 l1 = *(const bf16x4*)&Hl[hr][hk + 4];
            ah[ti] = __builtin_shufflevector(h0, h1, 0, 1, 2, 3, 4, 5, 6, 7);
            al[ti] = __builtin_shufflevector(l0, l1, 0, 1, 2, 3, 4, 5, 6, 7);
        }
#pragma unroll
        for (int ct = 0; ct < 2; ++ct) {
            const size_t woff = (size_t)(cq + ct * 16 + l15) * IN_DIM + k0 + quad * 8;
            bf16x8 wh = *(const bf16x8*)(Wb_h + woff);
            bf16x8 wl = *(const bf16x8*)(Wb_l + woff);
            acc[0][ct] = __builtin_amdgcn_mfma_f32_16x16x32_bf16(ah[0], wh, acc[0][ct], 0, 0, 0);
            acc[1][ct] = __builtin_amdgcn_mfma_f32_16x16x32_bf16(ah[1], wh, acc[1][ct], 0, 0, 0);
            acc[0][ct] = __builtin_amdgcn_mfma_f32_16x16x32_bf16(al[0], wh, acc[0][ct], 0, 0, 0);
            acc[1][ct] = __builtin_amdgcn_mfma_f32_16x16x32_bf16(al[1], wh, acc[1][ct], 0, 0, 0);
            acc[0][ct] = __builtin_amdgcn_mfma_f32_16x16x32_bf16(ah[0], wl, acc[0][ct], 0, 0, 0);
            acc[1][ct] = __builtin_amdgcn_mfma_f32_16x16x32_bf16(ah[1], wl, acc[1][ct], 0, 0, 0);
        }
    }

    // ---- epilogue 2: out = relu(acc + bb) -> global ----
#pragma unroll
    for (int ti = 0; ti < 2; ++ti) {
        const int rbase = brow + rh + ti * 16 + quad * 4;
#pragma unroll
        for (int ct = 0; ct < 2; ++ct) {
            int col = cq + ct * 16 + l15;
            float b = bb[col];
#pragma unroll
            for (int r = 0; r < 4; ++r) {
                int row = rbase + r;
                if (row < M) {
                    float o = fmaxf(acc[ti][ct][r] + b, 0.f);
                    if constexpr (LAYER == 1) {
                        unsigned short hh = bf16_rne(o);
                        Ch[(size_t)row * IN_DIM + col] = hh;
                        Cl[(size_t)row * IN_DIM + col] =
                            bf16_rne(o - __uint_as_float(((unsigned)hh) << 16));
                    } else {
                        C[(size_t)row * IN_DIM + col] = o;
                    }
                }
            }
        }
    }
}

// ---------------- pool + heads ---------------------------------------------

__device__ __forceinline__ int lower_bound_i(const int* __restrict__ a, int n, int v) {
    int lo = 0, hi = n;
    while (lo < hi) {
        int mid = (lo + hi) >> 1;
        if (a[mid] < v) lo = mid + 1; else hi = mid;
    }
    return lo;
}

__global__ __launch_bounds__(128) void pool_kernel(
    const float* __restrict__ h, const int* __restrict__ batch,
    float* __restrict__ pooled, int n_nodes, int n_graphs)
{
    int g = blockIdx.x;
    int lo = lower_bound_i(batch, n_nodes, g);
    int hi = lower_bound_i(batch, n_nodes, g + 1);
    int j = threadIdx.x;
    float acc = 0.f;
    for (int i = lo; i < hi; ++i)
        acc += h[(size_t)i * IN_DIM + j];
    float cnt = (float)(hi - lo);
    pooled[(size_t)g * IN_DIM + j] = acc / fmaxf(cnt, 1.0f);
}

__global__ __launch_bounds__(64) void head_kernel(
    const float* __restrict__ pooled,
    const float* __restrict__ Ws,  const float* __restrict__ bs,
    const float* __restrict__ WlS, const float* __restrict__ blS,
    const float* __restrict__ WlP, const float* __restrict__ blP,
    const float* __restrict__ WnR, const float* __restrict__ bnR,
    float* __restrict__ out, int n_graphs)
{
    int g = blockIdx.x;
    int j = threadIdx.x;
    const float* p = pooled + (size_t)g * IN_DIM;
    float acc = bs[j];
#pragma unroll 8
    for (int k = 0; k < IN_DIM; ++k)
        acc = fmaf(p[k], Ws[k * 64 + j], acc);
    float gj = fmaxf(acc, 0.f);
    float s1 = gj * WlS[j];
    float s2 = gj * WlP[j];
    float s3 = gj * WnR[j];
#pragma unroll
    for (int off = 32; off > 0; off >>= 1) {
        s1 += __shfl_down(s1, off);
        s2 += __shfl_down(s2, off);
        s3 += __shfl_down(s3, off);
    }
    if (j == 0) {
        out[g]                = s1 + blS[0];
        out[n_graphs + g]     = s2 + blP[0];
        out[2 * n_graphs + g] = s3 + bnR[0];
    }
}

// ---------------- launch ---------------------------------------------------

extern "C" void kernel_launch(void* const* d_in, const int* in_sizes, int n_in,
                              void* d_out, int out_size, void* d_ws, size_t ws_size,
                              hipStream_t stream)
{
    const float* x   = (const float*)d_in[0];
    const int*   ei  = (const int*)d_in[1];
    const int*   bat = (const int*)d_in[2];
    const float* W1a = (const float*)d_in[3];
    const float* b1a = (const float*)d_in[4];
    const float* W1b = (const float*)d_in[5];
    const float* b1b = (const float*)d_in[6];
    const float* W2a = (const float*)d_in[7];
    const float* b2a = (const float*)d_in[8];
    const float* W2b = (const float*)d_in[9];
    const float* b2b = (const float*)d_in[10];
    const float* Ws  = (const float*)d_in[11];
    const float* bs  = (const float*)d_in[12];
    const float* WlS = (const float*)d_in[13];
    const float* blS = (const float*)d_in[14];
    const float* WlP = (const float*)d_in[15];
    const float* blP = (const float*)d_in[16];
    const float* WnR = (const float*)d_in[17];
    const float* bnR = (const float*)d_in[18];

    const int n_nodes  = in_sizes[0] / IN_DIM;
    const int n_edges  = in_sizes[1] / 2;
    const int n_graphs = out_size / 3;
    const int* src = ei;
    const int* dst = ei + n_edges;

    const size_t node_elems   = (size_t)n_nodes * IN_DIM;
    const size_t pooled_elems = (size_t)n_graphs * IN_DIM;

    // ws layout:
    //   xb : bf16 of x            (node_elems ushort)
    //   Ch : layer-1 out high     (node_elems ushort)   [distinct from xb!]
    //   Cl : layer-1 out low      (node_elems ushort)
    //   P3 : layer-2 out fp32     (node_elems float)    [buckets alias here]
    //   pooled, row_start, bcur, csr_src, wt planes
    unsigned short* xb = (unsigned short*)d_ws;
    unsigned short* Ch = xb + node_elems;
    unsigned short* Cl = Ch + node_elems;
    float* P3     = (float*)(Cl + node_elems);
    float* pooled = P3 + node_elems;
    int* row_start = (int*)(pooled + pooled_elems);   // n_nodes + 1
    int* bcur      = row_start + (n_nodes + 1);       // NFINE bucket cursors
    int* csr_src   = bcur + NFINE;                    // n_edges
    unsigned short* wt_h = (unsigned short*)(csr_src + n_edges);  // 4 * 16384
    unsigned short* wt_l = wt_h + 4 * 16384;

    const int cap = n_edges / NFINE + 2048;           // ~18 sigma slack
    int2* buckets = (int2*)P3;                        // 128*cap*8B ~= 15MB

    const int layerblocks = (n_nodes + 63) / 64;
    const int binblocks = (n_edges + BIN_EPB - 1) / BIN_EPB;
    const int n8 = (int)(node_elems / 8);
    const int cvtblocks = (n8 + 255) / 256;

    // ---- weight conversion + CSR build ----
    conv_weights_kernel<<<256, 256, 0, stream>>>(W1a, W1b, W2a, W2b, wt_h, wt_l);
    hipMemsetAsync(bcur, 0, NFINE * sizeof(int), stream);
    bin_kernel<<<binblocks, 256, 0, stream>>>(src, dst, buckets, bcur,
                                              n_edges, n_nodes, cap);
    csr_fused_kernel<<<NFINE, 512, 0, stream>>>(buckets, bcur, row_start,
                                                csr_src, cap, n_nodes, n_edges);
    f32_to_bf16_kernel<<<cvtblocks, 256, 0, stream>>>((const float4*)x, (uint4*)xb, n8);

    // ---- layer 1 (fused gather + MLP) ----
    fused_gin_layer_kernel<1><<<layerblocks, 512, 0, stream>>>(
        x, nullptr, nullptr, (const uint4*)xb, row_start, csr_src,
        wt_h, wt_l, b1a, wt_h + 16384, wt_l + 16384, b1b,
        nullptr, Ch, Cl, n_nodes);

    // ---- layer 2 (fused gather + MLP) ----
    fused_gin_layer_kernel<2><<<layerblocks, 512, 0, stream>>>(
        nullptr, (const uint4*)Ch, (const uint4*)Cl, (const uint4*)Ch,
        row_start, csr_src,
        wt_h + 2 * 16384, wt_l + 2 * 16384, b2a,
        wt_h + 3 * 16384, wt_l + 3 * 16384, b2b,
        P3, nullptr, nullptr, n_nodes);

    // ---- pool + heads ----
    pool_kernel<<<n_graphs, 128, 0, stream>>>(P3, bat, pooled, n_nodes, n_graphs);
    head_kernel<<<n_graphs, 64, 0, stream>>>(pooled, Ws, bs, WlS, blS, WlP, blP,
                                             WnR, bnR, (float*)d_out, n_graphs);
}